// Round 4
// baseline (80.892 us; speedup 1.0000x reference)
//
#include <hip/hip_runtime.h>
#include <hip/hip_bf16.h>

typedef __attribute__((ext_vector_type(8))) short bf16x8;
typedef __attribute__((ext_vector_type(4))) float f32x4;

typedef const __attribute__((address_space(1))) void* gptr_t;
typedef __attribute__((address_space(3))) void* lptr_t;

#define NROW 8192
#define DDIM 256
#define HALF_B 4096
#define NB 64                        // 8192/128 tile bands
#define NTILES (NB * (NB + 1) / 2)   // 2080 upper-triangle tiles
#define GRIDSZ 512                   // persistent blocks (2 per CU)

// exp(dot/T) = exp2(dot * log2(e)/T), T = 0.07
#define E2SCALE 20.6099291555566196f
#define INV_T   14.2857142857142858f

// ---------------- kernel 1: row-normalize + bf16 cast + rowsum zero ---------
__global__ __launch_bounds__(256) void normalize_kernel(
    const float* __restrict__ z_i, const float* __restrict__ z_j,
    __hip_bfloat16* __restrict__ zn, float* __restrict__ rowsum) {
  const int lane = threadIdx.x & 63;
  const int w = blockIdx.x * 4 + (threadIdx.x >> 6);  // wave id 0..2047
  for (int row = w; row < NROW; row += 2048) {
    const float* src = (row < HALF_B) ? (z_i + (size_t)row * DDIM)
                                      : (z_j + (size_t)(row - HALF_B) * DDIM);
    float4 v = *reinterpret_cast<const float4*>(src + lane * 4);
    float ss = v.x * v.x + v.y * v.y + v.z * v.z + v.w * v.w;
#pragma unroll
    for (int m = 32; m; m >>= 1) ss += __shfl_xor(ss, m);
    float inv = 1.0f / sqrtf(ss);
    ushort4 o;
    {
      __hip_bfloat16 h;
      h = __float2bfloat16(v.x * inv); o.x = *reinterpret_cast<unsigned short*>(&h);
      h = __float2bfloat16(v.y * inv); o.y = *reinterpret_cast<unsigned short*>(&h);
      h = __float2bfloat16(v.z * inv); o.z = *reinterpret_cast<unsigned short*>(&h);
      h = __float2bfloat16(v.w * inv); o.w = *reinterpret_cast<unsigned short*>(&h);
    }
    *reinterpret_cast<ushort4*>(zn + (size_t)row * DDIM + lane * 4) = o;
    if (lane == 0) rowsum[row] = 0.0f;
  }
}

// ---------------- kernel 2: persistent upper-triangle 128x128 Gram tiles ----
// 256 thr = 4 waves (2x2), wave tile 64x64 (acc[4][4]). LDS double-buffered
// 2 x (A 16KB + B 16KB) = 64KB -> 2 blocks/CU. Cross-tile prefetch: at kt=3
// the next tile's kt=0 stage is issued, so epilogue overlaps in-flight loads.
// XOR-swizzle (16B chunks within 8-row stripes), both sides.
__global__ __launch_bounds__(256, 2) void gram_kernel(
    const __hip_bfloat16* __restrict__ zn,
    float* __restrict__ rowsum, float* __restrict__ pos) {
  __shared__ __hip_bfloat16 Asm[2 * 128 * 64];  // 32 KB (2 x 16 KB)
  __shared__ __hip_bfloat16 Bsm[2 * 128 * 64];  // 32 KB

  const int tid = threadIdx.x;
  const int lane = tid & 63;
  const int wid = tid >> 6;          // 0..3
  const int wr = wid >> 1;           // wave row 0..1 (64 rows each)
  const int wc = wid & 1;            // wave col 0..1 (64 cols each)

  const int csw = ((tid & 7) ^ ((tid >> 3) & 7)) * 8;  // pre-swizzled src col
  const int rloc = tid >> 3;                           // row in 32-row chunk

  auto decode = [](int p, int& by, int& bx) {
    by = 0;
    while (p >= NB - by) { p -= NB - by; ++by; }
    bx = by + p;
  };

  auto stage = [&](int rB, int cB, int kt, int b) {
#pragma unroll
    for (int t = 0; t < 4; ++t) {
      const int r = t * 32 + rloc;
      const __hip_bfloat16* ga = zn + (size_t)(rB + r) * DDIM + kt * 64 + csw;
      const __hip_bfloat16* gb = zn + (size_t)(cB + r) * DDIM + kt * 64 + csw;
      char* lA = reinterpret_cast<char*>(Asm) + b * 16384 + t * 4096 + wid * 1024;
      char* lB = reinterpret_cast<char*>(Bsm) + b * 16384 + t * 4096 + wid * 1024;
      __builtin_amdgcn_global_load_lds((gptr_t)ga, (lptr_t)lA, 16, 0, 0);
      __builtin_amdgcn_global_load_lds((gptr_t)gb, (lptr_t)lB, 16, 0, 0);
    }
  };

  int tile = blockIdx.x;
  if (tile >= NTILES) return;
  int by, bx;
  decode(tile, by, bx);
  int rowB = by * 128, colB = bx * 128;

  f32x4 acc[4][4] = {};
  stage(rowB, colB, 0, 0);
  int buf = 0;
  __syncthreads();

  const int xorv = (lane & 7) << 4;

  while (tile < NTILES) {
    const int ntile = tile + GRIDSZ;
    const bool hasnext = ntile < NTILES;
    int nrB = 0, ncB = 0;
    if (hasnext) {
      int nby, nbx;
      decode(ntile, nby, nbx);
      nrB = nby * 128; ncB = nbx * 128;
    }

    for (int kt = 0; kt < 4; ++kt) {
      if (kt < 3)           stage(rowB, colB, kt + 1, buf ^ 1);
      else if (hasnext)     stage(nrB, ncB, 0, buf ^ 1);

      const char* Ab = reinterpret_cast<const char*>(Asm) + buf * 16384;
      const char* Bb = reinterpret_cast<const char*>(Bsm) + buf * 16384;
#pragma unroll
      for (int kk = 0; kk < 2; ++kk) {
        bf16x8 af[4], bfr[4];
        const int kcolb = (kk * 32 + (lane >> 4) * 8) * 2;
#pragma unroll
        for (int m = 0; m < 4; ++m) {
          const int arow = wr * 64 + m * 16 + (lane & 15);
          af[m] = *reinterpret_cast<const bf16x8*>(
              Ab + (((arow << 7) + kcolb) ^ xorv));
        }
#pragma unroll
        for (int n = 0; n < 4; ++n) {
          const int brow = wc * 64 + n * 16 + (lane & 15);
          bfr[n] = *reinterpret_cast<const bf16x8*>(
              Bb + (((brow << 7) + kcolb) ^ xorv));
        }
#pragma unroll
        for (int m = 0; m < 4; ++m)
#pragma unroll
          for (int n = 0; n < 4; ++n)
            acc[m][n] = __builtin_amdgcn_mfma_f32_16x16x32_bf16(
                af[m], bfr[n], acc[m][n], 0, 0, 0);
      }
      __syncthreads();
      buf ^= 1;
    }

    // ---- epilogue (runs under the next tile's in-flight kt=0 loads)
    const bool isdiag = (colB == rowB);
    const bool ispos = (colB - rowB == HALF_B);
    float colpart[4] = {0.0f, 0.0f, 0.0f, 0.0f};
#pragma unroll
    for (int m = 0; m < 4; ++m) {
#pragma unroll
      for (int v = 0; v < 4; ++v) {
        const int gi = rowB + wr * 64 + m * 16 + (lane >> 4) * 4 + v;
        float rowpart = 0.0f;
#pragma unroll
        for (int n = 0; n < 4; ++n) {
          const float d = acc[m][n][v];
          float val = exp2f(d * E2SCALE);
          if (isdiag) {
            const int gj = colB + wc * 64 + n * 16 + (lane & 15);
            if (gi == gj) val = 0.0f;         // exclude diagonal
          } else if (ispos) {
            const int gj = colB + wc * 64 + n * 16 + (lane & 15);
            if (gj == gi + HALF_B) {          // positive pair
              const float pv = d * INV_T;
              pos[gi] = pv;
              pos[gj] = pv;
            }
          }
          rowpart += val;
          colpart[n] += val;
        }
        rowpart += __shfl_xor(rowpart, 1);
        rowpart += __shfl_xor(rowpart, 2);
        rowpart += __shfl_xor(rowpart, 4);
        rowpart += __shfl_xor(rowpart, 8);
        if ((lane & 15) == 0) atomicAdd(&rowsum[gi], rowpart);
      }
    }
    if (!isdiag) {
#pragma unroll
      for (int n = 0; n < 4; ++n) {
        float c = colpart[n];
        c += __shfl_xor(c, 16);
        c += __shfl_xor(c, 32);
        if (lane < 16) {
          const int gj = colB + wc * 64 + n * 16 + lane;
          atomicAdd(&rowsum[gj], c);
        }
      }
    }

    // reset accumulators for the next tile
#pragma unroll
    for (int m = 0; m < 4; ++m)
#pragma unroll
      for (int n = 0; n < 4; ++n)
        acc[m][n] = f32x4{0.0f, 0.0f, 0.0f, 0.0f};

    tile = ntile; rowB = nrB; colB = ncB;
  }
}

// ---------------- kernel 3: final loss reduction ----------------
__global__ __launch_bounds__(1024) void loss_kernel(
    const float* __restrict__ rowsum, const float* __restrict__ pos,
    float* __restrict__ out) {
  __shared__ float sred[16];
  float s = 0.0f;
  for (int i = threadIdx.x; i < NROW; i += 1024)
    s += logf(rowsum[i]) - pos[i];
#pragma unroll
  for (int m = 32; m; m >>= 1) s += __shfl_xor(s, m);
  if ((threadIdx.x & 63) == 0) sred[threadIdx.x >> 6] = s;
  __syncthreads();
  if (threadIdx.x < 16) {
    float t = sred[threadIdx.x];
#pragma unroll
    for (int m = 8; m; m >>= 1) t += __shfl_xor(t, m);
    if (threadIdx.x == 0) out[0] = t / (float)NROW;
  }
}

extern "C" void kernel_launch(void* const* d_in, const int* in_sizes, int n_in,
                              void* d_out, int out_size, void* d_ws, size_t ws_size,
                              hipStream_t stream) {
  const float* z_i = (const float*)d_in[0];
  const float* z_j = (const float*)d_in[1];
  float* out = (float*)d_out;

  char* ws = (char*)d_ws;
  __hip_bfloat16* zn = (__hip_bfloat16*)ws;                          // 4 MB
  float* rowsum = (float*)(ws + (size_t)NROW * DDIM * 2);            // 32 KB
  float* pos    = (float*)(ws + (size_t)NROW * DDIM * 2 + NROW * 4); // 32 KB

  normalize_kernel<<<512, 256, 0, stream>>>(z_i, z_j, zn, rowsum);
  gram_kernel<<<GRIDSZ, 256, 0, stream>>>(zn, rowsum, pos);
  loss_kernel<<<1, 1024, 0, stream>>>(rowsum, pos, out);
}

// Round 5
// 68.485 us; speedup vs baseline: 1.1812x; 1.1812x over previous
//
#include <hip/hip_runtime.h>
#include <hip/hip_bf16.h>

typedef __attribute__((ext_vector_type(8))) short bf16x8;
typedef __attribute__((ext_vector_type(4))) float f32x4;

typedef const __attribute__((address_space(1))) void* gptr_t;
typedef __attribute__((address_space(3))) void* lptr_t;

#define NROW 8192
#define DDIM 256
#define HALF_B 4096
#define NB 64                        // 8192/128 tile bands
#define NTILES (NB * (NB + 1) / 2)   // 2080 upper-triangle tiles

// exp(dot/T) = exp2(dot * log2(e)/T), T = 0.07
#define E2SCALE 20.6099291555566196f
#define INV_T   14.2857142857142858f

// ---------------- kernel 1: row-normalize + bf16 cast + zero P/loss ---------
__global__ __launch_bounds__(256) void normalize_kernel(
    const float* __restrict__ z_i, const float* __restrict__ z_j,
    __hip_bfloat16* __restrict__ zn, float4* __restrict__ P4,
    float* __restrict__ loss_accum) {
  const int lane = threadIdx.x & 63;
  const int w = blockIdx.x * 4 + (threadIdx.x >> 6);  // wave id 0..2047
  for (int row = w; row < NROW; row += 2048) {
    const float* src = (row < HALF_B) ? (z_i + (size_t)row * DDIM)
                                      : (z_j + (size_t)(row - HALF_B) * DDIM);
    float4 v = *reinterpret_cast<const float4*>(src + lane * 4);
    float ss = v.x * v.x + v.y * v.y + v.z * v.z + v.w * v.w;
#pragma unroll
    for (int m = 32; m; m >>= 1) ss += __shfl_xor(ss, m);
    float inv = 1.0f / sqrtf(ss);
    ushort4 o;
    {
      __hip_bfloat16 h;
      h = __float2bfloat16(v.x * inv); o.x = *reinterpret_cast<unsigned short*>(&h);
      h = __float2bfloat16(v.y * inv); o.y = *reinterpret_cast<unsigned short*>(&h);
      h = __float2bfloat16(v.z * inv); o.z = *reinterpret_cast<unsigned short*>(&h);
      h = __float2bfloat16(v.w * inv); o.w = *reinterpret_cast<unsigned short*>(&h);
    }
    *reinterpret_cast<ushort4*>(zn + (size_t)row * DDIM + lane * 4) = o;
  }
  // zero the partials matrix P (128 x 8192 f32 = 1M floats = 262144 float4)
  const int t = blockIdx.x * 256 + threadIdx.x;   // 0..131071
  const float4 z4 = {0.0f, 0.0f, 0.0f, 0.0f};
  P4[t] = z4;
  P4[t + 131072] = z4;
  if (t == 0) *loss_accum = 0.0f;
}

// ---------------- kernel 2: upper-triangle 128x128 Gram tiles ---------------
// 256 thr = 4 waves (2x2), wave tile 64x64 (acc[4][4]). Epilogue writes
// collision-free PLAIN stores into P[128][8192] — no atomics:
//   row-part of tile (by,bx), wave-col wc -> P[2*bx+wc][gi]
//   col-part of tile (by,bx), wave-row wr -> P[2*by+wr][gj]  (skipped on diag)
// XOR-swizzle (16B chunks within 8-row stripes), both sides.
__global__ __launch_bounds__(256) void gram_kernel(
    const __hip_bfloat16* __restrict__ zn,
    float* __restrict__ P, float* __restrict__ pos) {
  __shared__ __hip_bfloat16 Asm[128 * 64];   // 16 KB
  __shared__ __hip_bfloat16 Bsm[128 * 64];   // 16 KB

  const int tid = threadIdx.x;
  const int lane = tid & 63;
  const int wid = tid >> 6;          // 0..3
  const int wr = wid >> 1;           // wave row 0..1 (64 rows each)
  const int wc = wid & 1;            // wave col 0..1 (64 cols each)

  // decode upper-triangle block index: row-band by has (NB - by) blocks
  int p = blockIdx.x;
  int by = 0;
  while (p >= NB - by) { p -= NB - by; ++by; }
  const int bx = by + p;
  const int rowBase = by * 128;
  const int colBase = bx * 128;
  const bool isdiag = (bx == by);
  const bool ispos = (bx - by == 32);   // colBase == rowBase + HALF_B

  f32x4 acc[4][4] = {};

  const int csw = ((tid & 7) ^ ((tid >> 3) & 7)) * 8;  // pre-swizzled src col
  const int rloc = tid >> 3;                           // row in 32-row chunk

  for (int kt = 0; kt < 4; ++kt) {   // K = 256, BK = 64
#pragma unroll
    for (int t = 0; t < 4; ++t) {
      const int r = t * 32 + rloc;
      const __hip_bfloat16* ga = zn + (size_t)(rowBase + r) * DDIM + kt * 64 + csw;
      const __hip_bfloat16* gb = zn + (size_t)(colBase + r) * DDIM + kt * 64 + csw;
      char* lA = reinterpret_cast<char*>(Asm) + t * 4096 + wid * 1024;
      char* lB = reinterpret_cast<char*>(Bsm) + t * 4096 + wid * 1024;
      __builtin_amdgcn_global_load_lds((gptr_t)ga, (lptr_t)lA, 16, 0, 0);
      __builtin_amdgcn_global_load_lds((gptr_t)gb, (lptr_t)lB, 16, 0, 0);
    }
    __syncthreads();

    const char* Ab = reinterpret_cast<const char*>(Asm);
    const char* Bb = reinterpret_cast<const char*>(Bsm);
    const int xorv = (lane & 7) << 4;
#pragma unroll
    for (int kk = 0; kk < 2; ++kk) {
      bf16x8 af[4], bfr[4];
      const int kcolb = (kk * 32 + (lane >> 4) * 8) * 2;
      const int arow = wr * 64 + (lane & 15);
      const int brow = wc * 64 + (lane & 15);
#pragma unroll
      for (int m = 0; m < 4; ++m)
        af[m] = *reinterpret_cast<const bf16x8*>(
            Ab + ((((arow + m * 16) << 7) + kcolb) ^ xorv));
#pragma unroll
      for (int n = 0; n < 4; ++n)
        bfr[n] = *reinterpret_cast<const bf16x8*>(
            Bb + ((((brow + n * 16) << 7) + kcolb) ^ xorv));
#pragma unroll
      for (int m = 0; m < 4; ++m)
#pragma unroll
        for (int n = 0; n < 4; ++n)
          acc[m][n] = __builtin_amdgcn_mfma_f32_16x16x32_bf16(
              af[m], bfr[n], acc[m][n], 0, 0, 0);
    }
    __syncthreads();
  }

  // ---- epilogue: exp + row/col partial sums -> plain stores into P
  // C/D layout: col = lane&15, row = (lane>>4)*4 + v
  float* __restrict__ Prow = P + (size_t)(2 * bx + wc) * NROW;
  float* __restrict__ Pcol = P + (size_t)(2 * by + wr) * NROW;
  float colpart[4] = {0.0f, 0.0f, 0.0f, 0.0f};
#pragma unroll
  for (int m = 0; m < 4; ++m) {
#pragma unroll
    for (int v = 0; v < 4; ++v) {
      const int gi = rowBase + wr * 64 + m * 16 + (lane >> 4) * 4 + v;
      float rowpart = 0.0f;
#pragma unroll
      for (int n = 0; n < 4; ++n) {
        const float d = acc[m][n][v];
        float val = exp2f(d * E2SCALE);
        if (isdiag) {
          const int gj = colBase + wc * 64 + n * 16 + (lane & 15);
          if (gi == gj) val = 0.0f;          // exclude diagonal
        } else if (ispos) {
          const int gj = colBase + wc * 64 + n * 16 + (lane & 15);
          if (gj == gi + HALF_B) {           // positive pair
            const float pv = d * INV_T;
            pos[gi] = pv;
            pos[gj] = pv;
          }
        }
        rowpart += val;
        colpart[n] += val;
      }
      rowpart += __shfl_xor(rowpart, 1);
      rowpart += __shfl_xor(rowpart, 2);
      rowpart += __shfl_xor(rowpart, 4);
      rowpart += __shfl_xor(rowpart, 8);
      if ((lane & 15) == 0) Prow[gi] = rowpart;
    }
  }
  if (!isdiag) {
#pragma unroll
    for (int n = 0; n < 4; ++n) {
      float c = colpart[n];
      c += __shfl_xor(c, 16);
      c += __shfl_xor(c, 32);
      if (lane < 16) {
        const int gj = colBase + wc * 64 + n * 16 + lane;
        Pcol[gj] = c;
      }
    }
  }
}

// ---------------- kernel 3: row reduction + per-row log term ----------------
__global__ __launch_bounds__(128) void rowreduce_kernel(
    const float* __restrict__ P, const float* __restrict__ pos,
    float* __restrict__ loss_accum) {
  const int i = blockIdx.x * 128 + threadIdx.x;
  float s = 0.0f;
#pragma unroll 8
  for (int k = 0; k < 128; ++k) s += P[(size_t)k * NROW + i];
  float partial = logf(s) - pos[i];
#pragma unroll
  for (int m = 32; m; m >>= 1) partial += __shfl_xor(partial, m);
  __shared__ float w0;
  if (threadIdx.x == 0) w0 = partial;
  __syncthreads();
  if (threadIdx.x == 64) atomicAdd(loss_accum, partial + w0);
}

// ---------------- kernel 4: finalize ----------------
__global__ void finalize_kernel(const float* __restrict__ loss_accum,
                                float* __restrict__ out) {
  out[0] = loss_accum[0] * (1.0f / (float)NROW);
}

extern "C" void kernel_launch(void* const* d_in, const int* in_sizes, int n_in,
                              void* d_out, int out_size, void* d_ws, size_t ws_size,
                              hipStream_t stream) {
  const float* z_i = (const float*)d_in[0];
  const float* z_j = (const float*)d_in[1];
  float* out = (float*)d_out;

  char* ws = (char*)d_ws;
  __hip_bfloat16* zn = (__hip_bfloat16*)ws;                      // 4 MB
  float* pos  = (float*)(ws + 4194304);                          // 32 KB
  float* P    = (float*)(ws + 4194304 + 32768);                  // 4 MB
  float* lacc = (float*)(ws + 4194304 + 32768 + 4194304);        // 4 B

  normalize_kernel<<<512, 256, 0, stream>>>(z_i, z_j, zn, (float4*)P, lacc);
  gram_kernel<<<NTILES, 256, 0, stream>>>(zn, P, pos);
  rowreduce_kernel<<<NROW / 128, 128, 0, stream>>>(P, pos, lacc);
  finalize_kernel<<<1, 1, 0, stream>>>(lacc, out);
}

// Round 6
// 62.082 us; speedup vs baseline: 1.3030x; 1.1031x over previous
//
#include <hip/hip_runtime.h>
#include <hip/hip_bf16.h>

typedef __attribute__((ext_vector_type(8))) short bf16x8;
typedef __attribute__((ext_vector_type(4))) float f32x4;

typedef const __attribute__((address_space(1))) void* gptr_t;
typedef __attribute__((address_space(3))) void* lptr_t;

#define NROW 8192
#define DDIM 256
#define HALF_B 4096
#define NB 64                        // 8192/128 tile bands
#define NTILES (NB * (NB + 1) / 2)   // 2080 upper-triangle tiles

// exp(dot/T) = exp2(dot * log2(e)/T), T = 0.07
#define E2SCALE 20.6099291555566196f
#define INV_T   14.2857142857142858f

// ---------------- kernel 1: row-normalize + bf16 cast + zero P/loss ---------
__global__ __launch_bounds__(256) void normalize_kernel(
    const float* __restrict__ z_i, const float* __restrict__ z_j,
    __hip_bfloat16* __restrict__ zn, float4* __restrict__ P4,
    float* __restrict__ loss_accum) {
  const int lane = threadIdx.x & 63;
  const int w = blockIdx.x * 4 + (threadIdx.x >> 6);  // wave id 0..2047
  for (int row = w; row < NROW; row += 2048) {
    const float* src = (row < HALF_B) ? (z_i + (size_t)row * DDIM)
                                      : (z_j + (size_t)(row - HALF_B) * DDIM);
    float4 v = *reinterpret_cast<const float4*>(src + lane * 4);
    float ss = v.x * v.x + v.y * v.y + v.z * v.z + v.w * v.w;
#pragma unroll
    for (int m = 32; m; m >>= 1) ss += __shfl_xor(ss, m);
    float inv = 1.0f / sqrtf(ss);
    ushort4 o;
    {
      __hip_bfloat16 h;
      h = __float2bfloat16(v.x * inv); o.x = *reinterpret_cast<unsigned short*>(&h);
      h = __float2bfloat16(v.y * inv); o.y = *reinterpret_cast<unsigned short*>(&h);
      h = __float2bfloat16(v.z * inv); o.z = *reinterpret_cast<unsigned short*>(&h);
      h = __float2bfloat16(v.w * inv); o.w = *reinterpret_cast<unsigned short*>(&h);
    }
    *reinterpret_cast<ushort4*>(zn + (size_t)row * DDIM + lane * 4) = o;
  }
  // zero P (64 x 8192 f32 = 512K floats = 131072 float4) with 131072 threads
  const int t = blockIdx.x * 256 + threadIdx.x;
  P4[t] = float4{0.0f, 0.0f, 0.0f, 0.0f};
  if (t == 0) *loss_accum = 0.0f;
}

// ---------------- kernel 2: upper-triangle 128x128 Gram tiles ---------------
// 512 thr = 8 waves (2 row x 4 col), wave-tile 64x32 (acc[4][2] = 32 AGPR)
// -> ~110 unified regs/wave -> 16 waves/CU (2 blocks). Single-buffer LDS 32KB.
// Epilogue: intra-block LDS reduce (ds_add_f32) -> per-tile 256 floats:
//   row sums of tile (by,bx) -> P[bx][rows of band by]
//   col sums of tile (by,bx) -> P[by][cols of band bx]   (skipped on diag)
// Collision-free (proof: slot+band equality forces the diagonal tile).
// XOR-swizzle (16B chunks within 8-row stripes), both sides.
__global__ __launch_bounds__(512, 4) void gram_kernel(
    const __hip_bfloat16* __restrict__ zn,
    float* __restrict__ P, float* __restrict__ pos) {
  __shared__ __hip_bfloat16 Asm[128 * 64];   // 16 KB
  __shared__ __hip_bfloat16 Bsm[128 * 64];   // 16 KB
  __shared__ float rowbuf[128];
  __shared__ float colbuf[128];

  const int tid = threadIdx.x;
  const int lane = tid & 63;
  const int wid = tid >> 6;          // 0..7
  const int wr = wid >> 2;           // wave row 0..1 (64 rows each)
  const int wc = wid & 3;            // wave col 0..3 (32 cols each)

  // decode upper-triangle block index: row-band by has (NB - by) blocks
  int p = blockIdx.x;
  int by = 0;
  while (p >= NB - by) { p -= NB - by; ++by; }
  const int bx = by + p;
  const int rowBase = by * 128;
  const int colBase = bx * 128;
  const bool isdiag = (bx == by);
  const bool ispos = (bx - by == 32);   // colBase == rowBase + HALF_B

  if (tid < 128) rowbuf[tid] = 0.0f;
  else if (tid < 256) colbuf[tid - 128] = 0.0f;

  f32x4 acc[4][2] = {};

  // staging: per thread 16B x 2 issues per tile (A and B each):
  // linear LDS offset L = t*8192 + tid*16 -> row r = t*64 + (tid>>3),
  // col elem (tid&7)*8; source col pre-swizzled with r&7 = (tid>>3)&7
  const int csw = ((tid & 7) ^ ((tid >> 3) & 7)) * 8;
  const int rloc = tid >> 3;

  for (int kt = 0; kt < 4; ++kt) {   // K = 256, BK = 64
#pragma unroll
    for (int t = 0; t < 2; ++t) {
      const int r = t * 64 + rloc;
      const __hip_bfloat16* ga = zn + (size_t)(rowBase + r) * DDIM + kt * 64 + csw;
      const __hip_bfloat16* gb = zn + (size_t)(colBase + r) * DDIM + kt * 64 + csw;
      char* lA = reinterpret_cast<char*>(Asm) + t * 8192 + wid * 1024;
      char* lB = reinterpret_cast<char*>(Bsm) + t * 8192 + wid * 1024;
      __builtin_amdgcn_global_load_lds((gptr_t)ga, (lptr_t)lA, 16, 0, 0);
      __builtin_amdgcn_global_load_lds((gptr_t)gb, (lptr_t)lB, 16, 0, 0);
    }
    __syncthreads();

    const char* Ab = reinterpret_cast<const char*>(Asm);
    const char* Bb = reinterpret_cast<const char*>(Bsm);
    const int xorv = (lane & 7) << 4;
#pragma unroll
    for (int kk = 0; kk < 2; ++kk) {
      bf16x8 af[4], bfr[2];
      const int kcolb = (kk * 32 + (lane >> 4) * 8) * 2;
      const int arow = wr * 64 + (lane & 15);
      const int brow = wc * 32 + (lane & 15);
#pragma unroll
      for (int m = 0; m < 4; ++m)
        af[m] = *reinterpret_cast<const bf16x8*>(
            Ab + ((((arow + m * 16) << 7) + kcolb) ^ xorv));
#pragma unroll
      for (int n = 0; n < 2; ++n)
        bfr[n] = *reinterpret_cast<const bf16x8*>(
            Bb + ((((brow + n * 16) << 7) + kcolb) ^ xorv));
#pragma unroll
      for (int m = 0; m < 4; ++m)
#pragma unroll
        for (int n = 0; n < 2; ++n)
          acc[m][n] = __builtin_amdgcn_mfma_f32_16x16x32_bf16(
              af[m], bfr[n], acc[m][n], 0, 0, 0);
    }
    __syncthreads();
  }

  // ---- epilogue: exp + intra-block reduction via LDS float atomics
  // C/D layout: col = lane&15, row = (lane>>4)*4 + v
  float colpart[2] = {0.0f, 0.0f};
#pragma unroll
  for (int m = 0; m < 4; ++m) {
#pragma unroll
    for (int v = 0; v < 4; ++v) {
      const int lrow = wr * 64 + m * 16 + (lane >> 4) * 4 + v;
      const int gi = rowBase + lrow;
      float rowpart = 0.0f;
#pragma unroll
      for (int n = 0; n < 2; ++n) {
        const float d = acc[m][n][v];
        float val = exp2f(d * E2SCALE);
        if (isdiag) {
          const int gj = colBase + wc * 32 + n * 16 + (lane & 15);
          if (gi == gj) val = 0.0f;          // exclude diagonal
        } else if (ispos) {
          const int gj = colBase + wc * 32 + n * 16 + (lane & 15);
          if (gj == gi + HALF_B) {           // positive pair
            const float pv = d * INV_T;
            pos[gi] = pv;
            pos[gj] = pv;
          }
        }
        rowpart += val;
        colpart[n] += val;
      }
      rowpart += __shfl_xor(rowpart, 1);
      rowpart += __shfl_xor(rowpart, 2);
      rowpart += __shfl_xor(rowpart, 4);
      rowpart += __shfl_xor(rowpart, 8);
      if ((lane & 15) == 0) atomicAdd(&rowbuf[lrow], rowpart);
    }
  }
  if (!isdiag) {
#pragma unroll
    for (int n = 0; n < 2; ++n) {
      float c = colpart[n];
      c += __shfl_xor(c, 16);
      c += __shfl_xor(c, 32);
      if (lane < 16) atomicAdd(&colbuf[wc * 32 + n * 16 + lane], c);
    }
  }
  __syncthreads();

  // coalesced per-tile stores: 256 floats total
  if (tid < 128) {
    P[(size_t)bx * NROW + rowBase + tid] = rowbuf[tid];
  } else if (tid < 256 && !isdiag) {
    P[(size_t)by * NROW + colBase + tid - 128] = colbuf[tid - 128];
  }
}

// ---------------- kernel 3: row reduction + per-row log term ----------------
__global__ __launch_bounds__(256) void rowreduce_kernel(
    const float* __restrict__ P, const float* __restrict__ pos,
    float* __restrict__ loss_accum) {
  const int i = blockIdx.x * 256 + threadIdx.x;
  float s = 0.0f;
#pragma unroll 8
  for (int k = 0; k < NB; ++k) s += P[(size_t)k * NROW + i];
  float partial = logf(s) - pos[i];
#pragma unroll
  for (int m = 32; m; m >>= 1) partial += __shfl_xor(partial, m);
  __shared__ float sred[4];
  if ((threadIdx.x & 63) == 0) sred[threadIdx.x >> 6] = partial;
  __syncthreads();
  if (threadIdx.x == 0)
    atomicAdd(loss_accum, sred[0] + sred[1] + sred[2] + sred[3]);
}

// ---------------- kernel 4: finalize ----------------
__global__ void finalize_kernel(const float* __restrict__ loss_accum,
                                float* __restrict__ out) {
  out[0] = loss_accum[0] * (1.0f / (float)NROW);
}

extern "C" void kernel_launch(void* const* d_in, const int* in_sizes, int n_in,
                              void* d_out, int out_size, void* d_ws, size_t ws_size,
                              hipStream_t stream) {
  const float* z_i = (const float*)d_in[0];
  const float* z_j = (const float*)d_in[1];
  float* out = (float*)d_out;

  char* ws = (char*)d_ws;
  __hip_bfloat16* zn = (__hip_bfloat16*)ws;                      // 4 MB
  float* pos  = (float*)(ws + 4194304);                          // 32 KB
  float* P    = (float*)(ws + 4194304 + 32768);                  // 2 MB
  float* lacc = (float*)(ws + 4194304 + 32768 + 2097152);        // 4 B

  normalize_kernel<<<512, 256, 0, stream>>>(z_i, z_j, zn, (float4*)P, lacc);
  gram_kernel<<<NTILES, 512, 0, stream>>>(zn, P, pos);
  rowreduce_kernel<<<NROW / 256, 256, 0, stream>>>(P, pos, lacc);
  finalize_kernel<<<1, 1, 0, stream>>>(lacc, out);
}